// Round 4
// baseline (2035.164 us; speedup 1.0000x reference)
//
#include <hip/hip_runtime.h>

#define SEQ   1024
#define BATCH 512
#define HID   128
#define GC    512   // 4 gates * HID

typedef __attribute__((ext_vector_type(8))) short          short8v;
typedef __attribute__((ext_vector_type(4))) float          float4v;
typedef __attribute__((ext_vector_type(4))) unsigned short ushort4v;
typedef __attribute__((ext_vector_type(8))) unsigned short ushort8v;

__device__ __forceinline__ unsigned short f2bf(float f) {
    union { float f; unsigned u; } v; v.f = f;
    return (unsigned short)((v.u + 0x7fffu + ((v.u >> 16) & 1u)) >> 16);
}
__device__ __forceinline__ float bf2f(unsigned short u) {
    union { unsigned u; float f; } v; v.u = ((unsigned)u) << 16;
    return v.f;
}
__device__ __forceinline__ float fast_cos(float x) {
    return __builtin_amdgcn_cosf(x * 0.15915494309189535f);   // v_cos takes revolutions
}
__device__ __forceinline__ float fast_sigmoid(float x) {
    return __builtin_amdgcn_rcpf(1.0f + __builtin_amdgcn_exp2f(-1.4426950408889634f * x));
}
__device__ __forceinline__ float fast_tanh(float x) {
    return 1.0f - 2.0f * __builtin_amdgcn_rcpf(1.0f + __builtin_amdgcn_exp2f(2.8853900817779268f * x));
}

// raw barrier: drains LDS only; global loads/stores stay in flight across it
#define BAR() do { asm volatile("s_waitcnt lgkmcnt(0)" ::: "memory");  \
                   __builtin_amdgcn_s_barrier();                       \
                   __builtin_amdgcn_sched_barrier(0); } while (0)

// ---------------------------------------------------------------------------
// Kernel 0: X f32 -> bf16 streaming convert (chunk slice)
// ---------------------------------------------------------------------------
__global__ __launch_bounds__(256) void xbf_kernel(
    const float* __restrict__ X, unsigned short* __restrict__ Xb, int n8)
{
    int i = blockIdx.x * 256 + threadIdx.x;
    const int stride = gridDim.x * 256;
    for (; i < n8; i += stride) {
        float4v a = *(const float4v*)(X + (size_t)i * 8);
        float4v b = *(const float4v*)(X + (size_t)i * 8 + 4);
        ushort8v o;
        #pragma unroll
        for (int j = 0; j < 4; ++j) { o[j] = f2bf(a[j]); o[4 + j] = f2bf(b[j]); }
        *(ushort8v*)(Xb + (size_t)i * 8) = o;
    }
}

// ---------------------------------------------------------------------------
// Kernel 1: Z[row][col] = bf16( X[row][:] @ Wgate_x + b ).  X pre-cast bf16.
// 512 thr / WG, 128 rows / WG. Wave w -> Z cols [w*64,w*64+64). A = weight
// frags in regs; B = Xb rows, single b128 per ks. Body order keeps vmcnt
// waits counted (never drains stores).
// ---------------------------------------------------------------------------
__global__ __launch_bounds__(512, 4) void qlstm_xgemm(
    const unsigned short* __restrict__ Xb,   // [rows][128] bf16
    const float* __restrict__ Wf, const float* __restrict__ bfp,
    const float* __restrict__ Wi, const float* __restrict__ bip,
    const float* __restrict__ Wg, const float* __restrict__ bgp,
    const float* __restrict__ Wo, const float* __restrict__ bop,
    unsigned short* __restrict__ Z)
{
    const int tid = threadIdx.x, lane = tid & 63, wid = tid >> 6;
    const int l15 = lane & 15, kg = lane >> 4;
    const int g = wid >> 1;
    const float* Wsel = (g == 0) ? Wf : (g == 1) ? Wi : (g == 2) ? Wg : Wo;
    const float* bsel = (g == 0) ? bfp : (g == 1) ? bip : (g == 2) ? bgp : bop;
    const int cb  = (wid & 1) * 64;   // col base within gate
    const int zcb = wid * 64;         // col base within Z row

    short8v aw[4][4];                 // 64 VGPRs: W_x[k=0..127][cb+mt*16+l15]
    #pragma unroll
    for (int mt = 0; mt < 4; ++mt) {
        const int col = cb + mt * 16 + l15;
        #pragma unroll
        for (int ks = 0; ks < 4; ++ks) {
            const int k0 = ks * 32 + kg * 8;
            short8v a;
            #pragma unroll
            for (int j = 0; j < 8; ++j)
                a[j] = (short)f2bf(Wsel[(size_t)(k0 + j) * HID + col]);
            aw[mt][ks] = a;
        }
    }
    ushort4v biasb[4];                // bias as packed bf16 (Z is bf16 anyway)
    #pragma unroll
    for (int mt = 0; mt < 4; ++mt)
        #pragma unroll
        for (int j = 0; j < 4; ++j)
            biasb[mt][j] = f2bf(bsel[cb + mt * 16 + kg * 4 + j]);

    const int rowbase = blockIdx.x * 128;

    // preload rg=0 B-fragments
    short8v bx[4];
    {
        const unsigned short* xr = Xb + (size_t)(rowbase + l15) * HID;
        #pragma unroll
        for (int ks = 0; ks < 4; ++ks)
            bx[ks] = *(const short8v*)(xr + ks * 32 + kg * 8);
    }

    for (int rg = 0; rg < 8; ++rg) {
        float4v acc[4];
        #pragma unroll
        for (int mt = 0; mt < 4; ++mt)
            #pragma unroll
            for (int j = 0; j < 4; ++j) acc[mt][j] = bf2f(biasb[mt][j]);

        // MFMA on current bx (waits only on bx loads; stores stay outstanding)
        #pragma unroll
        for (int ks = 0; ks < 4; ++ks)
            #pragma unroll
            for (int mt = 0; mt < 4; ++mt)
                acc[mt] = __builtin_amdgcn_mfma_f32_16x16x32_bf16(aw[mt][ks], bx[ks], acc[mt], 0, 0, 0);

        // prefetch next rg's B (issued before this rg's stores)
        if (rg < 7) {
            const unsigned short* xr = Xb + (size_t)(rowbase + (rg + 1) * 16 + l15) * HID;
            #pragma unroll
            for (int ks = 0; ks < 4; ++ks)
                bx[ks] = *(const short8v*)(xr + ks * 32 + kg * 8);
        }

        const size_t zr = (size_t)(rowbase + rg * 16 + l15) * GC + zcb;
        #pragma unroll
        for (int mt = 0; mt < 4; ++mt) {
            ushort4v o;
            #pragma unroll
            for (int j = 0; j < 4; ++j) o[j] = f2bf(acc[mt][j]);
            *(ushort4v*)&Z[zr + mt * 16 + kg * 4] = o;
        }
    }
}

// ---------------------------------------------------------------------------
// Kernel 2: recurrent. 512 WGs x 512 thr (2 WGs/CU), 1 batch row per WG.
// Phase A: preact = Z[t] + h @ Wh via MFMA, then activations IN-REGISTER in
// the wave that computed them (gate is wave-uniform). f-gate cumprod: in-lane
// 4-chunk prefix + 2-shfl cross-kg scan; cross-wave fixup deferred to Phase D
// via one LDS scalar. Phase D on waves 2-3: cell update, out/h writes.
// ---------------------------------------------------------------------------
__global__ __launch_bounds__(512, 4) void qlstm_rec(
    const unsigned short* __restrict__ Z,   // [chunk][BATCH][GC] bf16
    const float* __restrict__ Wf, const float* __restrict__ Wi,
    const float* __restrict__ Wg, const float* __restrict__ Wo,
    float* __restrict__ out,
    unsigned short* __restrict__ hstate,    // bf16 [BATCH][HID]
    float* __restrict__ cstate,             // f32  [BATCH][HID]
    int t0, int chunk, int last)
{
    __shared__ float gact[GC];              // activated gates, flat col layout
    __shared__ alignas(16) unsigned short h_bf[HID];
    __shared__ float w0tot_s;               // wave0's total cumprod (f-gate)

    const int tid = threadIdx.x, lane = tid & 63, wid = tid >> 6;
    const int l15 = lane & 15, kg = lane >> 4;
    const int b = blockIdx.x;               // batch row
    const int g = wid >> 1;
    const float* Wsel = (g == 0) ? Wf : (g == 1) ? Wi : (g == 2) ? Wg : Wo;
    const int cb  = (wid & 1) * 64;
    const int zcb = wid * 64;

    short8v aw[4][4];                 // 64 VGPRs: W_h[k=128..255][cb+mt*16+l15]
    #pragma unroll
    for (int mt = 0; mt < 4; ++mt) {
        const int col = cb + mt * 16 + l15;
        #pragma unroll
        for (int ks = 0; ks < 4; ++ks) {
            const int k0 = 128 + ks * 32 + kg * 8;
            short8v a;
            #pragma unroll
            for (int j = 0; j < 8; ++j)
                a[j] = (short)f2bf(Wsel[(size_t)(k0 + j) * HID + col]);
            aw[mt][ks] = a;
        }
    }

    if (tid < 128) h_bf[tid] = hstate[(size_t)b * HID + tid];

    const bool pd = (wid == 2 || wid == 3);    // Phase-D waves (i-gate: lightest)
    const int  dcol = (wid & 1) * 64 + lane;   // col 0..127 for pd waves
    float c_reg = 0.f, h_last = 0.f;
    if (pd) c_reg = cstate[(size_t)b * HID + dcol];

    // prefetch Z[t=0]; address has no l15 dependence (all N-slots identical)
    ushort4v zpre[4];
    {
        const unsigned short* zb = Z + (size_t)b * GC + zcb;
        #pragma unroll
        for (int mt = 0; mt < 4; ++mt) zpre[mt] = *(const ushort4v*)(zb + mt * 16 + kg * 4);
    }

    BAR();

    for (int t = 0; t < chunk; ++t) {
        // ---- Phase A: MFMA (all 8 waves) ----
        short8v bh[4];
        #pragma unroll
        for (int ks = 0; ks < 4; ++ks)
            bh[ks] = *(const short8v*)&h_bf[ks * 32 + kg * 8];   // broadcast read

        float4v acc[4];
        #pragma unroll
        for (int mt = 0; mt < 4; ++mt)
            #pragma unroll
            for (int j = 0; j < 4; ++j) acc[mt][j] = bf2f(zpre[mt][j]);

        {   // prefetch Z[t+1]; flies across both barriers (raw barrier, counted vmcnt)
            const int tn = (t + 1 < chunk) ? (t + 1) : t;
            const unsigned short* zb = Z + ((size_t)tn * BATCH + b) * GC + zcb;
            #pragma unroll
            for (int mt = 0; mt < 4; ++mt) zpre[mt] = *(const ushort4v*)(zb + mt * 16 + kg * 4);
        }

        __builtin_amdgcn_s_setprio(1);
        #pragma unroll
        for (int ks = 0; ks < 4; ++ks)
            #pragma unroll
            for (int mt = 0; mt < 4; ++mt)
                acc[mt] = __builtin_amdgcn_mfma_f32_16x16x32_bf16(aw[mt][ks], bh[ks], acc[mt], 0, 0, 0);
        __builtin_amdgcn_s_setprio(0);

        // ---- Phase B: in-register activations (gate is wave-uniform) ----
        if (g == 0) {
            // cumprod of cos over this wave's 64 cols; col = zcb + mt*16 + kg*4 + j
            float M = 1.f;   // product of all chunks before current mt
            #pragma unroll
            for (int mt = 0; mt < 4; ++mt) {
                const float c0 = fast_cos(acc[mt][0]);
                const float c1 = fast_cos(acc[mt][1]);
                const float c2 = fast_cos(acc[mt][2]);
                const float c3 = fast_cos(acc[mt][3]);
                const float q0 = c0, q1 = q0 * c1, q2 = q1 * c2, q3 = q2 * c3;
                float v = q3;                         // chunk total (chunk = (mt,kg))
                float s = __shfl_up(v, 16); if (kg >= 1) v *= s;
                s = __shfl_up(v, 32);       if (kg >= 2) v *= s;   // incl over kg
                const float e = __shfl_up(v, 16);
                const float excl = (kg == 0) ? 1.f : e;
                const float G = __shfl(v, 48 + l15);  // total over kg for this mt
                const float pref = M * excl;
                acc[mt][0] = pref * q0; acc[mt][1] = pref * q1;
                acc[mt][2] = pref * q2; acc[mt][3] = pref * q3;
                M *= G;
            }
            if (wid == 0 && lane == 0) w0tot_s = M;   // wave0 total for cols 64-127
        } else if (g == 1) {
            #pragma unroll
            for (int mt = 0; mt < 4; ++mt)
                #pragma unroll
                for (int j = 0; j < 4; ++j) acc[mt][j] = (fast_cos(acc[mt][j]) + 1.f) * 0.5f;
        } else if (g == 2) {
            #pragma unroll
            for (int mt = 0; mt < 4; ++mt)
                #pragma unroll
                for (int j = 0; j < 4; ++j) acc[mt][j] = fast_tanh(acc[mt][j]);
        } else {
            #pragma unroll
            for (int mt = 0; mt < 4; ++mt)
                #pragma unroll
                for (int j = 0; j < 4; ++j) acc[mt][j] = fast_sigmoid(acc[mt][j]);
        }
        if (l15 == 0) {   // all l15 groups identical; one writes. conflict-free b128
            #pragma unroll
            for (int mt = 0; mt < 4; ++mt)
                *(float4v*)&gact[zcb + mt * 16 + kg * 4] = acc[mt];
        }
        BAR();  // S1: gact + w0tot ready

        // ---- Phase D: cell update (waves 2-3; 1 col/lane) ----
        if (pd) {
            float fr = gact[dcol];
            if (wid == 3) fr *= w0tot_s;              // cross-wave cumprod fixup
            const float f  = (fr + 1.f) * 0.5f;
            const float i_ = gact[128 + dcol];
            const float g_ = gact[256 + dcol];
            const float o_ = gact[384 + dcol];
            const float cn = fmaf(f, c_reg, i_ * g_);
            const float hn = o_ * fast_tanh(cn);
            c_reg = cn; h_last = hn;
            h_bf[dcol] = f2bf(hn);
            out[((size_t)(t0 + t) * BATCH + b) * HID + dcol] = hn;
        }
        BAR();  // S2: h_bf ready for next step
    }

    // save state; final hx/cx tails (bit-exact copies of last-step values)
    if (pd) {
        hstate[(size_t)b * HID + dcol] = f2bf(h_last);
        cstate[(size_t)b * HID + dcol] = c_reg;
        if (last) {
            const size_t base = (size_t)SEQ * BATCH * HID;
            out[base + (size_t)b * HID + dcol] = h_last;
            out[base + (size_t)BATCH * HID + (size_t)b * HID + dcol] = c_reg;
        }
    }
}

// ---------------------------------------------------------------------------
extern "C" void kernel_launch(void* const* d_in, const int* in_sizes, int n_in,
                              void* d_out, int out_size, void* d_ws, size_t ws_size,
                              hipStream_t stream) {
    const float* X  = (const float*)d_in[0];
    const float* Wf = (const float*)d_in[1];
    const float* bf = (const float*)d_in[2];
    const float* Wi = (const float*)d_in[3];
    const float* bi = (const float*)d_in[4];
    const float* Wg = (const float*)d_in[5];
    const float* bg = (const float*)d_in[6];
    const float* Wo = (const float*)d_in[7];
    const float* bo = (const float*)d_in[8];
    float* out = (float*)d_out;

    char* ws = (char*)d_ws;
    unsigned short* hstate = (unsigned short*)ws;                 // 128 KB used
    float*          cstate = (float*)(ws + 256 * 1024);           // 256 KB
    char*           dynws  = ws + 1024 * 1024;

    // per-step: Xbf 512*128*2 = 128 KB, Z 512*512*2 = 512 KB
    const size_t xstep = (size_t)BATCH * HID * sizeof(unsigned short);
    const size_t zstep = (size_t)BATCH * GC  * sizeof(unsigned short);
    size_t cap = (ws_size > (1u << 20)) ? ws_size - (1u << 20) : 0;
    int Tc = (int)(cap / (xstep + zstep));
    if (Tc > SEQ) Tc = SEQ;
    if (Tc < 1)   Tc = 1;

    hipMemsetAsync(ws, 0, 1024 * 1024, stream);   // zero h/c state

    for (int t0 = 0; t0 < SEQ; t0 += Tc) {
        const int chunk = (SEQ - t0 < Tc) ? (SEQ - t0) : Tc;
        unsigned short* Xbf  = (unsigned short*)dynws;
        unsigned short* Zbuf = (unsigned short*)(dynws + (size_t)chunk * xstep);

        const int n8 = chunk * BATCH * HID / 8;
        xbf_kernel<<<2048, 256, 0, stream>>>(
            X + (size_t)t0 * BATCH * HID, Xbf, n8);
        qlstm_xgemm<<<chunk * BATCH / 128, 512, 0, stream>>>(
            Xbf, Wf, bf, Wi, bi, Wg, bg, Wo, bo, Zbuf);
        qlstm_rec<<<BATCH, 512, 0, stream>>>(
            Zbuf, Wf, Wi, Wg, Wo, out, hstate, cstate,
            t0, chunk, (t0 + chunk == SEQ) ? 1 : 0);
    }
}

// Round 5
// 1580.522 us; speedup vs baseline: 1.2877x; 1.2877x over previous
//
#include <hip/hip_runtime.h>

#define SEQ   1024
#define BATCH 512
#define HID   128
#define GC    512   // 4 gates * HID

typedef __attribute__((ext_vector_type(8))) short          short8v;
typedef __attribute__((ext_vector_type(4))) float          float4v;
typedef __attribute__((ext_vector_type(4))) unsigned short ushort4v;
typedef __attribute__((ext_vector_type(8))) unsigned short ushort8v;

__device__ __forceinline__ unsigned short f2bf(float f) {
    union { float f; unsigned u; } v; v.f = f;
    return (unsigned short)((v.u + 0x7fffu + ((v.u >> 16) & 1u)) >> 16);
}
__device__ __forceinline__ float bf2f(unsigned short u) {
    union { unsigned u; float f; } v; v.u = ((unsigned)u) << 16;
    return v.f;
}
__device__ __forceinline__ float fast_cos(float x) {
    return __builtin_amdgcn_cosf(x * 0.15915494309189535f);   // v_cos takes revolutions
}
__device__ __forceinline__ float fast_sigmoid(float x) {
    return __builtin_amdgcn_rcpf(1.0f + __builtin_amdgcn_exp2f(-1.4426950408889634f * x));
}
__device__ __forceinline__ float fast_tanh(float x) {
    return 1.0f - 2.0f * __builtin_amdgcn_rcpf(1.0f + __builtin_amdgcn_exp2f(2.8853900817779268f * x));
}

// raw barrier: drains LDS only; global loads/stores stay in flight across it
#define BAR() do { asm volatile("s_waitcnt lgkmcnt(0)" ::: "memory");  \
                   __builtin_amdgcn_s_barrier();                       \
                   __builtin_amdgcn_sched_barrier(0); } while (0)

// ---------------------------------------------------------------------------
// Kernel 0: X f32 -> bf16 streaming convert (chunk slice)
// ---------------------------------------------------------------------------
__global__ __launch_bounds__(256) void xbf_kernel(
    const float* __restrict__ X, unsigned short* __restrict__ Xb, int n8)
{
    int i = blockIdx.x * 256 + threadIdx.x;
    const int stride = gridDim.x * 256;
    for (; i < n8; i += stride) {
        float4v a = *(const float4v*)(X + (size_t)i * 8);
        float4v b = *(const float4v*)(X + (size_t)i * 8 + 4);
        ushort8v o;
        #pragma unroll
        for (int j = 0; j < 4; ++j) { o[j] = f2bf(a[j]); o[4 + j] = f2bf(b[j]); }
        *(ushort8v*)(Xb + (size_t)i * 8) = o;
    }
}

// ---------------------------------------------------------------------------
// Kernel 1: Z[row][g*128+c] = bf16( Xb[row][:] @ Wg_x[:,c] + b ).  (unchanged R4)
// ---------------------------------------------------------------------------
__global__ __launch_bounds__(512, 4) void qlstm_xgemm(
    const unsigned short* __restrict__ Xb,   // [rows][128] bf16
    const float* __restrict__ Wf, const float* __restrict__ bfp,
    const float* __restrict__ Wi, const float* __restrict__ bip,
    const float* __restrict__ Wg, const float* __restrict__ bgp,
    const float* __restrict__ Wo, const float* __restrict__ bop,
    unsigned short* __restrict__ Z)
{
    const int tid = threadIdx.x, lane = tid & 63, wid = tid >> 6;
    const int l15 = lane & 15, kg = lane >> 4;
    const int g = wid >> 1;
    const float* Wsel = (g == 0) ? Wf : (g == 1) ? Wi : (g == 2) ? Wg : Wo;
    const float* bsel = (g == 0) ? bfp : (g == 1) ? bip : (g == 2) ? bgp : bop;
    const int cb  = (wid & 1) * 64;   // col base within gate
    const int zcb = wid * 64;         // col base within Z row

    short8v aw[4][4];                 // W_x[k=0..127][cb+mt*16+l15]
    #pragma unroll
    for (int mt = 0; mt < 4; ++mt) {
        const int col = cb + mt * 16 + l15;
        #pragma unroll
        for (int ks = 0; ks < 4; ++ks) {
            const int k0 = ks * 32 + kg * 8;
            short8v a;
            #pragma unroll
            for (int j = 0; j < 8; ++j)
                a[j] = (short)f2bf(Wsel[(size_t)(k0 + j) * HID + col]);
            aw[mt][ks] = a;
        }
    }
    ushort4v biasb[4];
    #pragma unroll
    for (int mt = 0; mt < 4; ++mt)
        #pragma unroll
        for (int j = 0; j < 4; ++j)
            biasb[mt][j] = f2bf(bsel[cb + mt * 16 + kg * 4 + j]);

    const int rowbase = blockIdx.x * 128;

    short8v bx[4];
    {
        const unsigned short* xr = Xb + (size_t)(rowbase + l15) * HID;
        #pragma unroll
        for (int ks = 0; ks < 4; ++ks)
            bx[ks] = *(const short8v*)(xr + ks * 32 + kg * 8);
    }

    for (int rg = 0; rg < 8; ++rg) {
        float4v acc[4];
        #pragma unroll
        for (int mt = 0; mt < 4; ++mt)
            #pragma unroll
            for (int j = 0; j < 4; ++j) acc[mt][j] = bf2f(biasb[mt][j]);

        #pragma unroll
        for (int ks = 0; ks < 4; ++ks)
            #pragma unroll
            for (int mt = 0; mt < 4; ++mt)
                acc[mt] = __builtin_amdgcn_mfma_f32_16x16x32_bf16(aw[mt][ks], bx[ks], acc[mt], 0, 0, 0);

        if (rg < 7) {
            const unsigned short* xr = Xb + (size_t)(rowbase + (rg + 1) * 16 + l15) * HID;
            #pragma unroll
            for (int ks = 0; ks < 4; ++ks)
                bx[ks] = *(const short8v*)(xr + ks * 32 + kg * 8);
        }

        const size_t zr = (size_t)(rowbase + rg * 16 + l15) * GC + zcb;
        #pragma unroll
        for (int mt = 0; mt < 4; ++mt) {
            ushort4v o;
            #pragma unroll
            for (int j = 0; j < 4; ++j) o[j] = f2bf(acc[mt][j]);
            *(ushort4v*)&Z[zr + mt * 16 + kg * 4] = o;
        }
    }
}

// ---------------------------------------------------------------------------
// Kernel 2: recurrent. 256 WGs x 512 thr, 2 batch rows/WG (rows in N-slots).
// Wave w owns cols [w*16, w*16+16) of ALL FOUR gates (4 MFMA tiles). After
// MFMA, lane (l15=row, kg) holds f/i/g/o preacts for its 4 cols -> the whole
// activation + cell update + h/out write is in-register in that lane.
// f-cumprod: in-lane prefix + 2-shfl kg-scan + 8-slot LDS cross-wave prefix.
// ---------------------------------------------------------------------------
__global__ __launch_bounds__(512, 2) void qlstm_rec(
    const unsigned short* __restrict__ Z,   // [chunk][BATCH][GC] bf16
    const float* __restrict__ Wf, const float* __restrict__ Wi,
    const float* __restrict__ Wg, const float* __restrict__ Wo,
    float* __restrict__ out,
    unsigned short* __restrict__ hstate,    // bf16 [BATCH][HID]
    float* __restrict__ cstate,             // f32  [BATCH][HID]
    int t0, int chunk, int last)
{
    __shared__ float scanW[8][2];           // per-wave f-chunk products (row 0/1)
    __shared__ alignas(16) unsigned short h_bf[2][HID];

    const int tid = threadIdx.x, lane = tid & 63, wid = tid >> 6;
    const int l15 = lane & 15, kg = lane >> 4;
    const int b0 = blockIdx.x * 2;          // batch rows b0, b0+1
    const int colb = wid * 16;              // this wave's col-block (per gate)
    const int row  = (l15 < 2) ? l15 : 1;
    const bool actv = (l15 < 2);
    const int mycol0 = colb + kg * 4;       // this lane's 4 cols (per gate)

    // A frags: aw[g][ks] = W_g[128 + ks*32 + kg*8 + j][colb + l15]
    short8v aw[4][4];
    #pragma unroll
    for (int g = 0; g < 4; ++g) {
        const float* Wsel = (g == 0) ? Wf : (g == 1) ? Wi : (g == 2) ? Wg : Wo;
        const int col = colb + l15;
        #pragma unroll
        for (int ks = 0; ks < 4; ++ks) {
            const int k0 = 128 + ks * 32 + kg * 8;
            short8v a;
            #pragma unroll
            for (int j = 0; j < 8; ++j)
                a[j] = (short)f2bf(Wsel[(size_t)(k0 + j) * HID + col]);
            aw[g][ks] = a;
        }
    }

    if (tid < 256) h_bf[tid >> 7][tid & 127] = hstate[(size_t)(b0 + (tid >> 7)) * HID + (tid & 127)];

    float c_reg[4], hL[4];
    #pragma unroll
    for (int j = 0; j < 4; ++j) { c_reg[j] = 0.f; hL[j] = 0.f; }
    if (actv) {
        #pragma unroll
        for (int j = 0; j < 4; ++j)
            c_reg[j] = cstate[(size_t)(b0 + row) * HID + mycol0 + j];
    }

    // prefetch Z[t=0]: zpre[g] = Z[b0+row][g*128 + mycol0 .. +3]
    ushort4v zpre[4];
    {
        const unsigned short* zb = Z + (size_t)(b0 + row) * GC;
        #pragma unroll
        for (int g = 0; g < 4; ++g)
            zpre[g] = *(const ushort4v*)(zb + g * 128 + mycol0);
    }

    BAR();

    for (int t = 0; t < chunk; ++t) {
        // ---- Phase A: MFMA ----
        short8v bh[4];
        #pragma unroll
        for (int ks = 0; ks < 4; ++ks)
            bh[ks] = *(const short8v*)&h_bf[row][ks * 32 + kg * 8];

        float4v acc[4];
        #pragma unroll
        for (int g = 0; g < 4; ++g)
            #pragma unroll
            for (int j = 0; j < 4; ++j) acc[g][j] = bf2f(zpre[g][j]);

        {   // prefetch Z[t+1]; flies across both barriers (raw barrier)
            const int tn = (t + 1 < chunk) ? (t + 1) : t;
            const unsigned short* zb = Z + ((size_t)tn * BATCH + b0 + row) * GC;
            #pragma unroll
            for (int g = 0; g < 4; ++g)
                zpre[g] = *(const ushort4v*)(zb + g * 128 + mycol0);
        }

        __builtin_amdgcn_s_setprio(1);
        #pragma unroll
        for (int ks = 0; ks < 4; ++ks)
            #pragma unroll
            for (int g = 0; g < 4; ++g)
                acc[g] = __builtin_amdgcn_mfma_f32_16x16x32_bf16(aw[g][ks], bh[ks], acc[g], 0, 0, 0);
        __builtin_amdgcn_s_setprio(0);

        // ---- Phase B: in-register activations ----
        // f-gate: cumprod of cos over cols (wave-major, then kg, then j = col order)
        const float fc0 = fast_cos(acc[0][0]);
        const float fc1 = fast_cos(acc[0][1]);
        const float fc2 = fast_cos(acc[0][2]);
        const float fc3 = fast_cos(acc[0][3]);
        const float q0 = fc0, q1 = q0 * fc1, q2 = q1 * fc2, q3 = q2 * fc3;
        float v = q3;
        float s = __shfl_up(v, 16); if (kg >= 1) v *= s;
        s = __shfl_up(v, 32);       if (kg >= 2) v *= s;    // inclusive over kg
        const float e = __shfl_up(v, 16);
        const float excl = (kg == 0) ? 1.f : e;             // exclusive over kg
        if (kg == 3 && actv) scanW[wid][l15] = v;           // wave total (this row)

        float iv[4], gv[4], ov[4];
        #pragma unroll
        for (int j = 0; j < 4; ++j) {
            iv[j] = (fast_cos(acc[1][j]) + 1.f) * 0.5f;
            gv[j] = fast_tanh(acc[2][j]);
            ov[j] = fast_sigmoid(acc[3][j]);
        }
        BAR();  // S1: scanW ready

        // cross-wave exclusive prefix: 8 parallel LDS reads + predicated muls
        float sw[8];
        #pragma unroll
        for (int jw = 0; jw < 8; ++jw) sw[jw] = scanW[jw][row];
        float P = excl;
        #pragma unroll
        for (int jw = 0; jw < 8; ++jw) P *= (jw < wid) ? sw[jw] : 1.f;

        // ---- Phase C: cell update, fully in-lane ----
        const float qs0 = P * q0, qs1 = P * q1, qs2 = P * q2, qs3 = P * q3;
        float hn[4];
        {
            const float f0 = (qs0 + 1.f) * 0.5f;
            const float f1 = (qs1 + 1.f) * 0.5f;
            const float f2 = (qs2 + 1.f) * 0.5f;
            const float f3 = (qs3 + 1.f) * 0.5f;
            const float cn0 = fmaf(f0, c_reg[0], iv[0] * gv[0]);
            const float cn1 = fmaf(f1, c_reg[1], iv[1] * gv[1]);
            const float cn2 = fmaf(f2, c_reg[2], iv[2] * gv[2]);
            const float cn3 = fmaf(f3, c_reg[3], iv[3] * gv[3]);
            hn[0] = ov[0] * fast_tanh(cn0);
            hn[1] = ov[1] * fast_tanh(cn1);
            hn[2] = ov[2] * fast_tanh(cn2);
            hn[3] = ov[3] * fast_tanh(cn3);
            c_reg[0] = cn0; c_reg[1] = cn1; c_reg[2] = cn2; c_reg[3] = cn3;
        }

        if (actv) {
            ushort4v hp;
            #pragma unroll
            for (int j = 0; j < 4; ++j) { hp[j] = f2bf(hn[j]); hL[j] = hn[j]; }
            *(ushort4v*)&h_bf[row][mycol0] = hp;
            float4v o4;
            #pragma unroll
            for (int j = 0; j < 4; ++j) o4[j] = hn[j];
            *(float4v*)&out[((size_t)(t0 + t) * BATCH + b0 + row) * HID + mycol0] = o4;
        }
        BAR();  // S2: h_bf ready for next step
    }

    // save state; final hx/cx tails
    if (actv) {
        #pragma unroll
        for (int j = 0; j < 4; ++j) {
            hstate[(size_t)(b0 + row) * HID + mycol0 + j] = f2bf(hL[j]);
            cstate[(size_t)(b0 + row) * HID + mycol0 + j] = c_reg[j];
        }
        if (last) {
            const size_t base = (size_t)SEQ * BATCH * HID;
            const size_t ro = (size_t)(b0 + row) * HID + mycol0;
            float4v h4, c4;
            #pragma unroll
            for (int j = 0; j < 4; ++j) { h4[j] = hL[j]; c4[j] = c_reg[j]; }
            *(float4v*)&out[base + ro] = h4;
            *(float4v*)&out[base + (size_t)BATCH * HID + ro] = c4;
        }
    }
}

// ---------------------------------------------------------------------------
extern "C" void kernel_launch(void* const* d_in, const int* in_sizes, int n_in,
                              void* d_out, int out_size, void* d_ws, size_t ws_size,
                              hipStream_t stream) {
    const float* X  = (const float*)d_in[0];
    const float* Wf = (const float*)d_in[1];
    const float* bf = (const float*)d_in[2];
    const float* Wi = (const float*)d_in[3];
    const float* bi = (const float*)d_in[4];
    const float* Wg = (const float*)d_in[5];
    const float* bg = (const float*)d_in[6];
    const float* Wo = (const float*)d_in[7];
    const float* bo = (const float*)d_in[8];
    float* out = (float*)d_out;

    char* ws = (char*)d_ws;
    unsigned short* hstate = (unsigned short*)ws;                 // 128 KB used
    float*          cstate = (float*)(ws + 256 * 1024);           // 256 KB
    char*           dynws  = ws + 1024 * 1024;

    const size_t xstep = (size_t)BATCH * HID * sizeof(unsigned short);  // 128 KB
    const size_t zstep = (size_t)BATCH * GC  * sizeof(unsigned short);  // 512 KB
    size_t cap = (ws_size > (1u << 20)) ? ws_size - (1u << 20) : 0;
    int Tc = (int)(cap / (xstep + zstep));
    if (Tc > SEQ) Tc = SEQ;
    if (Tc < 1)   Tc = 1;

    hipMemsetAsync(ws, 0, 1024 * 1024, stream);   // zero h/c state

    for (int t0 = 0; t0 < SEQ; t0 += Tc) {
        const int chunk = (SEQ - t0 < Tc) ? (SEQ - t0) : Tc;
        unsigned short* Xbf  = (unsigned short*)dynws;
        unsigned short* Zbuf = (unsigned short*)(dynws + (size_t)chunk * xstep);

        const int n8 = chunk * BATCH * HID / 8;
        xbf_kernel<<<2048, 256, 0, stream>>>(
            X + (size_t)t0 * BATCH * HID, Xbf, n8);
        qlstm_xgemm<<<chunk * BATCH / 128, 512, 0, stream>>>(
            Xbf, Wf, bf, Wi, bi, Wg, bg, Wo, bo, Zbuf);
        qlstm_rec<<<BATCH / 2, 512, 0, stream>>>(
            Zbuf, Wf, Wi, Wg, Wo, out, hstate, cstate,
            t0, chunk, (t0 + chunk == SEQ) ? 1 : 0);
    }
}

// Round 6
// 1456.633 us; speedup vs baseline: 1.3972x; 1.0851x over previous
//
#include <hip/hip_runtime.h>

#define SEQ   1024
#define BATCH 512
#define HID   128
#define GC    512   // 4 gates * HID

typedef __attribute__((ext_vector_type(8))) short          short8v;
typedef __attribute__((ext_vector_type(4))) float          float4v;
typedef __attribute__((ext_vector_type(2))) float          float2v;
typedef __attribute__((ext_vector_type(4))) unsigned short ushort4v;
typedef __attribute__((ext_vector_type(8))) unsigned short ushort8v;

__device__ __forceinline__ unsigned short f2bf(float f) {
    union { float f; unsigned u; } v; v.f = f;
    return (unsigned short)((v.u + 0x7fffu + ((v.u >> 16) & 1u)) >> 16);
}
__device__ __forceinline__ float bf2f(unsigned short u) {
    union { unsigned u; float f; } v; v.u = ((unsigned)u) << 16;
    return v.f;
}
__device__ __forceinline__ float fast_cos(float x) {
    return __builtin_amdgcn_cosf(x * 0.15915494309189535f);   // v_cos takes revolutions
}
__device__ __forceinline__ float fast_sigmoid(float x) {
    return __builtin_amdgcn_rcpf(1.0f + __builtin_amdgcn_exp2f(-1.4426950408889634f * x));
}
__device__ __forceinline__ float fast_tanh(float x) {
    return 1.0f - 2.0f * __builtin_amdgcn_rcpf(1.0f + __builtin_amdgcn_exp2f(2.8853900817779268f * x));
}

// DPP helper: returns src shifted by CTRL, invalid/masked lanes get 1.0f
template<int CTRL, int RM>
__device__ __forceinline__ float dpp1(float v) {
    union { float f; int i; } s, o, r;
    s.f = v; o.f = 1.0f;
    r.i = __builtin_amdgcn_update_dpp(o.i, s.i, CTRL, RM, 0xf, false);
    return r.f;
}

// raw barrier: drains LDS only; global loads/stores stay in flight across it
#define BAR() do { asm volatile("s_waitcnt lgkmcnt(0)" ::: "memory");  \
                   __builtin_amdgcn_s_barrier();                       \
                   __builtin_amdgcn_sched_barrier(0); } while (0)

// ---------------------------------------------------------------------------
// Kernel 0: X f32 -> bf16 streaming convert (chunk slice)
// ---------------------------------------------------------------------------
__global__ __launch_bounds__(256) void xbf_kernel(
    const float* __restrict__ X, unsigned short* __restrict__ Xb, int n8)
{
    int i = blockIdx.x * 256 + threadIdx.x;
    const int stride = gridDim.x * 256;
    for (; i < n8; i += stride) {
        float4v a = *(const float4v*)(X + (size_t)i * 8);
        float4v b = *(const float4v*)(X + (size_t)i * 8 + 4);
        ushort8v o;
        #pragma unroll
        for (int j = 0; j < 4; ++j) { o[j] = f2bf(a[j]); o[4 + j] = f2bf(b[j]); }
        *(ushort8v*)(Xb + (size_t)i * 8) = o;
    }
}

// ---------------------------------------------------------------------------
// Kernel 1: Z[row][g*128+c] = bf16( Xb[row][:] @ Wg_x[:,c] + b ).  (unchanged)
// ---------------------------------------------------------------------------
__global__ __launch_bounds__(512, 4) void qlstm_xgemm(
    const unsigned short* __restrict__ Xb,   // [rows][128] bf16
    const float* __restrict__ Wf, const float* __restrict__ bfp,
    const float* __restrict__ Wi, const float* __restrict__ bip,
    const float* __restrict__ Wg, const float* __restrict__ bgp,
    const float* __restrict__ Wo, const float* __restrict__ bop,
    unsigned short* __restrict__ Z)
{
    const int tid = threadIdx.x, lane = tid & 63, wid = tid >> 6;
    const int l15 = lane & 15, kg = lane >> 4;
    const int g = wid >> 1;
    const float* Wsel = (g == 0) ? Wf : (g == 1) ? Wi : (g == 2) ? Wg : Wo;
    const float* bsel = (g == 0) ? bfp : (g == 1) ? bip : (g == 2) ? bgp : bop;
    const int cb  = (wid & 1) * 64;
    const int zcb = wid * 64;

    short8v aw[4][4];
    #pragma unroll
    for (int mt = 0; mt < 4; ++mt) {
        const int col = cb + mt * 16 + l15;
        #pragma unroll
        for (int ks = 0; ks < 4; ++ks) {
            const int k0 = ks * 32 + kg * 8;
            short8v a;
            #pragma unroll
            for (int j = 0; j < 8; ++j)
                a[j] = (short)f2bf(Wsel[(size_t)(k0 + j) * HID + col]);
            aw[mt][ks] = a;
        }
    }
    ushort4v biasb[4];
    #pragma unroll
    for (int mt = 0; mt < 4; ++mt)
        #pragma unroll
        for (int j = 0; j < 4; ++j)
            biasb[mt][j] = f2bf(bsel[cb + mt * 16 + kg * 4 + j]);

    const int rowbase = blockIdx.x * 128;

    short8v bx[4];
    {
        const unsigned short* xr = Xb + (size_t)(rowbase + l15) * HID;
        #pragma unroll
        for (int ks = 0; ks < 4; ++ks)
            bx[ks] = *(const short8v*)(xr + ks * 32 + kg * 8);
    }

    for (int rg = 0; rg < 8; ++rg) {
        float4v acc[4];
        #pragma unroll
        for (int mt = 0; mt < 4; ++mt)
            #pragma unroll
            for (int j = 0; j < 4; ++j) acc[mt][j] = bf2f(biasb[mt][j]);

        #pragma unroll
        for (int ks = 0; ks < 4; ++ks)
            #pragma unroll
            for (int mt = 0; mt < 4; ++mt)
                acc[mt] = __builtin_amdgcn_mfma_f32_16x16x32_bf16(aw[mt][ks], bx[ks], acc[mt], 0, 0, 0);

        if (rg < 7) {
            const unsigned short* xr = Xb + (size_t)(rowbase + (rg + 1) * 16 + l15) * HID;
            #pragma unroll
            for (int ks = 0; ks < 4; ++ks)
                bx[ks] = *(const short8v*)(xr + ks * 32 + kg * 8);
        }

        const size_t zr = (size_t)(rowbase + rg * 16 + l15) * GC + zcb;
        #pragma unroll
        for (int mt = 0; mt < 4; ++mt) {
            ushort4v o;
            #pragma unroll
            for (int j = 0; j < 4; ++j) o[j] = f2bf(acc[mt][j]);
            *(ushort4v*)&Z[zr + mt * 16 + kg * 4] = o;
        }
    }
}

// ---------------------------------------------------------------------------
// Kernel 2: recurrent. 512 WGs x 256 thr (4 waves), 1 batch row/WG,
// 2 WGs/CU co-resident -> independent chains overlap each other's stalls.
// Phase A: wave g computes gate g's h@Wh. A = h broadcast into all 16 M
// slots (D rows identical, every lane valid), B = Wh frags in regs.
// kg==0 lanes publish 128 preacts/gate to gpre.
// Phase B: ONE worker wave (wid == blockIdx&3, staggers SIMDs across
// co-resident WGs): 2 cols/lane, Z added in-register (prefetched), cumprod
// via 4 DPP row_shr mul-scan + 3 shfl row-total broadcasts, cell update,
// h_bf b32 write, out float2 write. 2 barriers/step.
// ---------------------------------------------------------------------------
__global__ __launch_bounds__(256, 2) void qlstm_rec(
    const unsigned short* __restrict__ Z,   // [chunk][BATCH][GC] bf16
    const float* __restrict__ Wf, const float* __restrict__ Wi,
    const float* __restrict__ Wg, const float* __restrict__ Wo,
    float* __restrict__ out,
    unsigned short* __restrict__ hstate,    // bf16 [BATCH][HID]
    float* __restrict__ cstate,             // f32  [BATCH][HID]
    int t0, int chunk, int last)
{
    __shared__ float gpre[4][HID];          // h@Wh preacts per gate
    __shared__ alignas(16) unsigned short h_bf[HID];

    const int tid = threadIdx.x, lane = tid & 63, wid = tid >> 6;
    const int l15 = lane & 15, kg = lane >> 4;
    const int b = blockIdx.x;               // batch row
    const float* Wsel = (wid == 0) ? Wf : (wid == 1) ? Wi : (wid == 2) ? Wg : Wo;
    const bool worker = (wid == (blockIdx.x & 3));

    // B-frags: bw[n][ks] = W[128 + ks*32 + kg*8 + j][n*16 + l15]   (128 VGPR)
    short8v bw[8][4];
    #pragma unroll
    for (int n = 0; n < 8; ++n) {
        const int col = n * 16 + l15;
        #pragma unroll
        for (int ks = 0; ks < 4; ++ks) {
            const int k0 = 128 + ks * 32 + kg * 8;
            short8v a;
            #pragma unroll
            for (int j = 0; j < 8; ++j)
                a[j] = (short)f2bf(Wsel[(size_t)(k0 + j) * HID + col]);
            bw[n][ks] = a;
        }
    }

    if (tid < HID) h_bf[tid] = hstate[(size_t)b * HID + tid];

    float c0 = 0.f, c1 = 0.f, hL0 = 0.f, hL1 = 0.f;
    unsigned zp[4];
    #pragma unroll
    for (int g = 0; g < 4; ++g) zp[g] = 0;
    if (worker) {
        c0 = cstate[(size_t)b * HID + 2 * lane];
        c1 = cstate[(size_t)b * HID + 2 * lane + 1];
        #pragma unroll
        for (int g = 0; g < 4; ++g)   // z for cols {2*lane, 2*lane+1} of gate g
            zp[g] = *(const unsigned*)&Z[(size_t)b * GC + g * HID + 2 * lane];
    }

    BAR();

    for (int t = 0; t < chunk; ++t) {
        // ---- Phase A: h @ Wh, gate = wid ----
        short8v ah[4];                      // A-frag: h broadcast (all M slots)
        #pragma unroll
        for (int ks = 0; ks < 4; ++ks)
            ah[ks] = *(const short8v*)&h_bf[ks * 32 + kg * 8];

        float4v acc[8];
        #pragma unroll
        for (int n = 0; n < 8; ++n)
            #pragma unroll
            for (int j = 0; j < 4; ++j) acc[n][j] = 0.f;

        __builtin_amdgcn_s_setprio(1);
        #pragma unroll
        for (int ks = 0; ks < 4; ++ks)
            #pragma unroll
            for (int n = 0; n < 8; ++n)
                acc[n] = __builtin_amdgcn_mfma_f32_16x16x32_bf16(ah[ks], bw[n][ks], acc[n], 0, 0, 0);
        __builtin_amdgcn_s_setprio(0);

        if (kg == 0) {                      // 16 lanes publish 128 preacts
            #pragma unroll
            for (int n = 0; n < 8; ++n)
                gpre[wid][n * 16 + l15] = acc[n][0];
        }
        BAR();  // S1: gpre ready

        // ---- Phase B: worker wave only; cols {2*lane, 2*lane+1} ----
        if (worker) {
            const float pf0 = gpre[0][2 * lane]     + bf2f((unsigned short)(zp[0] & 0xffffu));
            const float pf1 = gpre[0][2 * lane + 1] + bf2f((unsigned short)(zp[0] >> 16));
            const float pi0 = gpre[1][2 * lane]     + bf2f((unsigned short)(zp[1] & 0xffffu));
            const float pi1 = gpre[1][2 * lane + 1] + bf2f((unsigned short)(zp[1] >> 16));
            const float pg0 = gpre[2][2 * lane]     + bf2f((unsigned short)(zp[2] & 0xffffu));
            const float pg1 = gpre[2][2 * lane + 1] + bf2f((unsigned short)(zp[2] >> 16));
            const float po0 = gpre[3][2 * lane]     + bf2f((unsigned short)(zp[3] & 0xffffu));
            const float po1 = gpre[3][2 * lane + 1] + bf2f((unsigned short)(zp[3] >> 16));

            {   // prefetch Z[t+1]; flies across both barriers (raw barrier)
                const int tn = (t + 1 < chunk) ? (t + 1) : t;
                const unsigned short* zb = Z + ((size_t)tn * BATCH + b) * GC + 2 * lane;
                #pragma unroll
                for (int g = 0; g < 4; ++g)
                    zp[g] = *(const unsigned*)(zb + g * HID);
            }

            // f-gate cumprod over 128 cols: pair product -> 64-lane mul-scan
            const float fc0 = fast_cos(pf0), fc1 = fast_cos(pf1);
            const float pair = fc0 * fc1;
            float R = pair;
            R *= dpp1<0x111, 0xf>(R);       // row_shr:1
            R *= dpp1<0x112, 0xf>(R);       // row_shr:2
            R *= dpp1<0x114, 0xf>(R);       // row_shr:4
            R *= dpp1<0x118, 0xf>(R);       // row_shr:8  (16-lane incl scan)
            const float Erow = dpp1<0x111, 0xf>(R);             // within-row excl
            const float T0 = __shfl(R, 15);                     // row totals
            const float T1 = __shfl(R, 31);
            const float T2 = __shfl(R, 47);
            const float rp = (kg == 0) ? 1.f : (kg == 1) ? T0
                           : (kg == 2) ? T0 * T1 : T0 * T1 * T2;
            const float E  = Erow * rp;                         // excl prefix
            const float f0 = (E * fc0  + 1.f) * 0.5f;
            const float f1 = (E * pair + 1.f) * 0.5f;

            const float i0 = (fast_cos(pi0) + 1.f) * 0.5f;
            const float i1 = (fast_cos(pi1) + 1.f) * 0.5f;
            const float g0 = fast_tanh(pg0);
            const float g1 = fast_tanh(pg1);
            const float o0 = fast_sigmoid(po0);
            const float o1 = fast_sigmoid(po1);

            const float cn0 = fmaf(f0, c0, i0 * g0);
            const float cn1 = fmaf(f1, c1, i1 * g1);
            const float hn0 = o0 * fast_tanh(cn0);
            const float hn1 = o1 * fast_tanh(cn1);
            c0 = cn0; c1 = cn1; hL0 = hn0; hL1 = hn1;

            *(unsigned*)&h_bf[2 * lane] =
                (unsigned)f2bf(hn0) | ((unsigned)f2bf(hn1) << 16);
            float2v ov; ov[0] = hn0; ov[1] = hn1;
            *(float2v*)&out[((size_t)(t0 + t) * BATCH + b) * HID + 2 * lane] = ov;
        }
        BAR();  // S2: h_bf ready for next step
    }

    // save state; final hx/cx tails
    if (worker) {
        hstate[(size_t)b * HID + 2 * lane]     = f2bf(hL0);
        hstate[(size_t)b * HID + 2 * lane + 1] = f2bf(hL1);
        cstate[(size_t)b * HID + 2 * lane]     = c0;
        cstate[(size_t)b * HID + 2 * lane + 1] = c1;
        if (last) {
            const size_t base = (size_t)SEQ * BATCH * HID;
            const size_t ro = (size_t)b * HID + 2 * lane;
            float2v h2, c2;
            h2[0] = hL0; h2[1] = hL1; c2[0] = c0; c2[1] = c1;
            *(float2v*)&out[base + ro] = h2;
            *(float2v*)&out[base + (size_t)BATCH * HID + ro] = c2;
        }
    }
}

// ---------------------------------------------------------------------------
extern "C" void kernel_launch(void* const* d_in, const int* in_sizes, int n_in,
                              void* d_out, int out_size, void* d_ws, size_t ws_size,
                              hipStream_t stream) {
    const float* X  = (const float*)d_in[0];
    const float* Wf = (const float*)d_in[1];
    const float* bf = (const float*)d_in[2];
    const float* Wi = (const float*)d_in[3];
    const float* bi = (const float*)d_in[4];
    const float* Wg = (const float*)d_in[5];
    const float* bg = (const float*)d_in[6];
    const float* Wo = (const float*)d_in[7];
    const float* bo = (const float*)d_in[8];
    float* out = (float*)d_out;

    char* ws = (char*)d_ws;
    unsigned short* hstate = (unsigned short*)ws;                 // 128 KB used
    float*          cstate = (float*)(ws + 256 * 1024);           // 256 KB
    char*           dynws  = ws + 1024 * 1024;

    const size_t xstep = (size_t)BATCH * HID * sizeof(unsigned short);  // 128 KB
    const size_t zstep = (size_t)BATCH * GC  * sizeof(unsigned short);  // 512 KB
    size_t cap = (ws_size > (1u << 20)) ? ws_size - (1u << 20) : 0;
    int Tc = (int)(cap / (xstep + zstep));
    if (Tc > SEQ) Tc = SEQ;
    if (Tc < 1)   Tc = 1;

    hipMemsetAsync(ws, 0, 1024 * 1024, stream);   // zero h/c state

    for (int t0 = 0; t0 < SEQ; t0 += Tc) {
        const int chunk = (SEQ - t0 < Tc) ? (SEQ - t0) : Tc;
        unsigned short* Xbf  = (unsigned short*)dynws;
        unsigned short* Zbuf = (unsigned short*)(dynws + (size_t)chunk * xstep);

        const int n8 = chunk * BATCH * HID / 8;
        xbf_kernel<<<2048, 256, 0, stream>>>(
            X + (size_t)t0 * BATCH * HID, Xbf, n8);
        qlstm_xgemm<<<chunk * BATCH / 128, 512, 0, stream>>>(
            Xbf, Wf, bf, Wi, bi, Wg, bg, Wo, bo, Zbuf);
        qlstm_rec<<<BATCH, 256, 0, stream>>>(
            Zbuf, Wf, Wi, Wg, Wo, out, hstate, cstate,
            t0, chunk, (t0 + chunk == SEQ) ? 1 : 0);
    }
}